// Round 11
// baseline (430.757 us; speedup 1.0000x reference)
//
#include <hip/hip_runtime.h>
#include <math.h>

typedef __bf16 bf16x8 __attribute__((ext_vector_type(8)));
typedef __bf16 bf16x4 __attribute__((ext_vector_type(4)));
typedef float  f32x4  __attribute__((ext_vector_type(4)));

__device__ __forceinline__ float silu_f(float x){ return x / (1.f + __expf(-x)); }
__device__ __forceinline__ float sigm_f(float x){ return 1.f / (1.f + __expf(-x)); }

// prep: W2 (fp32 [64][2560]) -> W2t (bf16 [kc][2560][32]); hist: count dst
__global__ void __launch_bounds__(256) k_setup(const float* __restrict__ W2,
    __bf16* __restrict__ W2t, const int* __restrict__ ei, int* __restrict__ cnt,
    int nbPrep, int E){
  int b = blockIdx.x, t = threadIdx.x;
  if (b < nbPrep){
    int gid = b*256 + t;   // 163840 total
    int h = gid / 2560;
    int col = gid - h*2560;
    W2t[(size_t)(h>>5)*81920 + col*32 + (h&31)] = (__bf16)W2[gid];
  } else {
    int e = (b - nbPrep)*256 + t;
    if (e < E) atomicAdd(&cnt[ei[E+e]], 1);
  }
}

__global__ void __launch_bounds__(1024) k_scan(const int* __restrict__ cnt,
    int* __restrict__ rowp, int* __restrict__ cursor, int N, int E){
  __shared__ int part[1024];
  int t = threadIdx.x;
  int chunk = (N + 1023) >> 10;
  int lo = t*chunk, hi = min(lo+chunk, N);
  int s = 0;
  for (int i = lo; i < hi; ++i) s += cnt[i];
  part[t] = s;
  __syncthreads();
  for (int off = 1; off < 1024; off <<= 1){
    int v = (t >= off) ? part[t-off] : 0;
    __syncthreads();
    part[t] += v;
    __syncthreads();
  }
  int base = (t == 0) ? 0 : part[t-1];
  for (int i = lo; i < hi; ++i){
    rowp[i] = base; cursor[i] = base;
    base += cnt[i];
  }
  if (t == 1023) rowp[N] = E;
}

// 16 edges / 256-thread block. bf16 coef tables (8 blocks/CU), wave-specialized
// col ranges, DEPTH-2 B/b2 prefetch, b2 folded into MFMA C-init, scalar coef
// hoisted (read per r, not per tile), cVt [r][quad][16] aligned layout,
// CSR placement fused (cursor atomics), CSR-ordered output.
__global__ void __launch_bounds__(256) k_edge(
    const float* __restrict__ nf, const int* __restrict__ ei,
    const float* __restrict__ sh, const float* __restrict__ radial,
    const float* __restrict__ env,
    const float* __restrict__ W1, const float* __restrict__ b1,
    const __bf16* __restrict__ W2t, const float* __restrict__ b2,
    const float* __restrict__ Wq, const float* __restrict__ bq,
    const float* __restrict__ Wk, const float* __restrict__ bk,
    int* __restrict__ cursor,
    float* __restrict__ msgs, float* __restrict__ logits_s, int E)
{
  __shared__ __bf16 u_lds[16][72];                 // 2304 B
  __shared__ float uniA[1360];                     // featT[80][17] <-> macc[16][84]
  __shared__ __bf16 cABt[48][20];                  // 1920 B
  __shared__ __align__(16) char uniB[8192];        // w1l f32[1024] <-> cVt2 bf16[64][4][16]
  __shared__ float shlT[4][17];
  __shared__ float radl[16][17];
  __shared__ float b1l[64];
  __shared__ int   src_l[16], dst_l[16], perm_l[16];

  float (*featT)[17] = (float(*)[17])uniA;
  float (*macc)[84]  = (float(*)[84])uniA;
  float* w1l = (float*)uniB;
  __bf16 (*cVt2)[4][16] = (__bf16(*)[4][16])uniB;  // [r][quad][c*4+reg], 16B-aligned rows

  const int t = threadIdx.x;
  const int e0 = blockIdx.x*16;

  // ---- stage 1: indices + fused CSR placement, sh, radial, W1, b1
  if (t < 16){
    int ee = e0 + t;
    if (ee < E){
      int sn = ei[ee], dn = ei[E+ee];
      src_l[t] = sn; dst_l[t] = dn;
      perm_l[t] = atomicAdd(&cursor[dn], 1);
    } else {
      int ec = E-1;
      src_l[t] = ei[ec]; dst_l[t] = ei[E+ec]; perm_l[t] = 0;
    }
  }
  if (t >= 64 && t < 128){
    int i = t-64; int e = i>>2, c = i&3;
    int ec = min(e0+e, E-1);
    shlT[c][e] = sh[(size_t)ec*4+c];
  }
  if (t >= 128 && t < 192) b1l[t-128] = b1[t-128];
  {
    int e = t>>4, r = t&15;
    int ec = min(e0+e, E-1);
    radl[e][r] = radial[(size_t)ec*16+r];
  }
  *(float4*)&w1l[t*4] = ((const float4*)W1)[t];
  __syncthreads();

  // ---- stage 2: featT (transposed) + u = silu(radial@W1+b1) -> bf16
  for (int i = t; i < 1280; i += 256){
    int e = i / 80, idx = i - e*80;
    featT[idx][e] = nf[(size_t)src_l[e]*80 + idx];
  }
  for (int i = t; i < 1024; i += 256){
    int e = i & 15, h = i >> 4;
    float acc = b1l[h];
    #pragma unroll
    for (int r = 0; r < 16; ++r) acc += radl[e][r]*w1l[r*64+h];
    u_lds[e][h] = (__bf16)silu_f(acc);
  }
  __syncthreads();

  const float inv_s3 = 0.57735026918962576f;
  const float inv_s2 = 0.70710678118654752f;
  const float a0 = 0.14433756729740643f;  // 1/sqrt(48)
  const float a1 = 0.125f;                // 1/sqrt(64)

  // ---- stage 3: coefficients (bf16); cVt2 overwrites dead w1l
  for (int i = t; i < 768; i += 256){
    int r = i >> 4, e = i & 15;
    float val;
    if (r < 32) val = a0 * shlT[0][e] * featT[r][e];
    else {
      int v = r - 32;
      float dot = (featT[32+v*3][e]*shlT[1][e] + featT[33+v*3][e]*shlT[2][e]
                 + featT[34+v*3][e]*shlT[3][e]) * inv_s3;
      val = a0 * dot;
    }
    cABt[r][e] = (__bf16)val;
  }
  __syncthreads();   // all w1l reads done before cVt2 overwrite
  for (int i = t; i < 3072; i += 256){
    int e = i & 15, r = (i >> 4) & 63, c = i >> 10;
    float val;
    if (r < 32) val = a1 * shlT[1+c][e] * featT[r][e];
    else if (r < 48){
      int v = r - 32;
      val = a1 * shlT[0][e] * featT[32+v*3+c][e];
    } else {
      int v = r - 48;
      int c1 = c+1; if (c1 > 2) c1 -= 3;
      int c2 = c+2; if (c2 > 2) c2 -= 3;
      val = a1 * inv_s2 * (featT[32+v*3+c1][e]*shlT[1+c2][e]
                         - featT[32+v*3+c2][e]*shlT[1+c1][e]);
    }
    cVt2[r][e>>2][c*4 + (e&3)] = (__bf16)val;
  }
  __syncthreads();

  // ---- zero macc (aliases featT, now dead)
  for (int i = t; i < 1344; i += 256) uniA[i] = 0.f;
  __syncthreads();

  // ---- stage 4: MFMA tile loop, wave-specialized, depth-2 prefetch
  const int lane = t & 63;
  const int wv   = t >> 6;
  const int quad = lane >> 4;
  const int nlo  = lane & 15;

  bf16x8 afr0 = *(const bf16x8*)&u_lds[nlo][quad*8];
  bf16x8 afr1 = *(const bf16x8*)&u_lds[nlo][32 + quad*8];

  const bool scalarW = (wv < 2);
  const int itBeg = scalarW ? wv*48 : 96 + (wv-2)*32;
  const int itEnd = scalarW ? itBeg + 48 : itBeg + 32;

  float accS0[4] = {0,0,0,0};
  float accS1[4] = {0,0,0,0};
  float accV0[4] = {0,0,0,0};
  float accV1[4] = {0,0,0,0};
  float accV2[4] = {0,0,0,0};

  const __bf16* bpBase = W2t + (size_t)nlo*32 + (size_t)quad*8;
  // depth-2 pipeline: cb = tile it, nb = tile it+1
  bf16x8 cb0 = *(const bf16x8*)(bpBase + (size_t)itBeg*512);
  bf16x8 cb1 = *(const bf16x8*)(bpBase + (size_t)itBeg*512 + 81920);
  float  cbc = b2[itBeg*16 + nlo];
  bf16x8 nb0 = *(const bf16x8*)(bpBase + (size_t)(itBeg+1)*512);
  bf16x8 nb1 = *(const bf16x8*)(bpBase + (size_t)(itBeg+1)*512 + 81920);
  float  nbc = b2[(itBeg+1)*16 + nlo];

  bf16x4 c4 = {};   // hoisted scalar coef (valid for tile pairs)

  for (int it = itBeg; it < itEnd; ++it){
    bf16x8 fb0 = nb0, fb1 = nb1; float fbc = nbc;
    if (it + 2 < itEnd){
      const __bf16* bp = bpBase + (size_t)(it+2)*512;
      fb0 = *(const bf16x8*)(bp);
      fb1 = *(const bf16x8*)(bp + 81920);
      fbc = b2[(it+2)*16 + nlo];
    }
    f32x4 d = {cbc, cbc, cbc, cbc};   // b2 folded into C-init
    d = __builtin_amdgcn_mfma_f32_16x16x32_bf16(afr0, cb0, d, 0, 0, 0);
    d = __builtin_amdgcn_mfma_f32_16x16x32_bf16(afr1, cb1, d, 0, 0, 0);
    if (scalarW){
      const int r = it >> 1;
      if (!(it & 1)){
        c4 = *(const bf16x4*)&cABt[r][quad*4];
        #pragma unroll
        for (int reg = 0; reg < 4; ++reg) accS0[reg] += (float)c4[reg]*d[reg];
      } else {
        #pragma unroll
        for (int reg = 0; reg < 4; ++reg) accS1[reg] += (float)c4[reg]*d[reg];
      }
    } else {
      const int r = it - 96;
      const bf16x8 v01 = *(const bf16x8*)&cVt2[r][quad][0];
      const bf16x4 v2  = *(const bf16x4*)&cVt2[r][quad][8];
      #pragma unroll
      for (int reg = 0; reg < 4; ++reg){
        accV0[reg] += (float)v01[reg]  *d[reg];
        accV1[reg] += (float)v01[4+reg]*d[reg];
        accV2[reg] += (float)v2[reg]   *d[reg];
      }
    }
    cb0 = nb0; cb1 = nb1; cbc = nbc;
    nb0 = fb0; nb1 = fb1; nbc = fbc;
  }

  // ---- cross-wave reduce into macc
  if (scalarW){
    #pragma unroll
    for (int reg = 0; reg < 4; ++reg){
      const int m = quad*4+reg;
      atomicAdd(&macc[m][nlo],    accS0[reg]);
      atomicAdd(&macc[m][16+nlo], accS1[reg]);
    }
  } else {
    #pragma unroll
    for (int reg = 0; reg < 4; ++reg){
      const int m = quad*4+reg;
      atomicAdd(&macc[m][32+nlo*3+0], accV0[reg]);
      atomicAdd(&macc[m][32+nlo*3+1], accV1[reg]);
      atomicAdd(&macc[m][32+nlo*3+2], accV2[reg]);
    }
  }
  __syncthreads();

  // ---- logits (waves 0-1: 8 edges each)
  if (t < 128){
    const int l = t & 63;
    const int e = (t >> 6)*8 + (l >> 3);
    const int kq = l & 7;
    const int eg = e0 + e;
    const bool act = (eg < E);
    float4 ms = *(const float4*)&macc[e][kq*4];
    int dn = dst_l[e];
    float4 qs = *(const float4*)(nf + (size_t)dn*80 + kq*4);
    float pk[8], pq[8];
    #pragma unroll
    for (int j = 0; j < 8; ++j){
      pk[j] = ms.x*Wk[(kq*4+0)*8+j] + ms.y*Wk[(kq*4+1)*8+j]
            + ms.z*Wk[(kq*4+2)*8+j] + ms.w*Wk[(kq*4+3)*8+j];
      pq[j] = qs.x*Wq[(kq*4+0)*8+j] + qs.y*Wq[(kq*4+1)*8+j]
            + qs.z*Wq[(kq*4+2)*8+j] + qs.w*Wq[(kq*4+3)*8+j];
    }
    #pragma unroll
    for (int m = 1; m < 8; m <<= 1){
      #pragma unroll
      for (int j = 0; j < 8; ++j){
        pk[j] += __shfl_xor(pk[j], m);
        pq[j] += __shfl_xor(pq[j], m);
      }
    }
    if (kq == 0 && act){
      float lg = 0.f;
      #pragma unroll
      for (int j = 0; j < 8; ++j) lg += (pq[j]+bq[j])*(pk[j]+bk[j]);
      lg *= 0.35355339059327373f;  // 1/sqrt(8)
      lg += logf(env[eg] + 1e-8f);
      logits_s[perm_l[e]] = lg;
    }
  }

  // ---- store messages in CSR order
  for (int i = t; i < 320; i += 256){
    int e = i/20, r = i - (i/20)*20;
    if (e0 + e < E)
      ((float4*)(msgs + (size_t)perm_l[e]*80))[r] = *(const float4*)&macc[e][r*4];
  }
}

// One wave per node: softmax over contiguous CSR range + coalesced gather,
// then fused node matmuls + gate + residual + BN stats.
__global__ void __launch_bounds__(256) k_agg(
    const float* __restrict__ msgs, const float* __restrict__ logits_s,
    const int* __restrict__ rowp, const float* __restrict__ nf,
    const float* __restrict__ Wout_s, const float* __restrict__ Wout_v,
    const float* __restrict__ Wg_s, const float* __restrict__ Wg_v,
    float* __restrict__ xbuf, float* __restrict__ bnacc, int N)
{
  __shared__ float aggl[4][80];
  __shared__ float t1[4][96];
  __shared__ float t2[4][96];
  __shared__ float bnl[80];
  const int t = threadIdx.x, l = t & 63, wv = t >> 6;
  const int n = blockIdx.x*4 + wv;
  const bool act = (n < N);
  const int nc = act ? n : (N-1);
  if (t < 80) bnl[t] = 0.f;

  const int r0 = rowp[nc], r1 = rowp[nc+1];
  const int deg = act ? (r1 - r0) : 0;

  float mym = -3.4e38f;
  for (int i = l; i < deg; i += 64) mym = fmaxf(mym, logits_s[r0+i]);
  #pragma unroll
  for (int s = 32; s; s >>= 1) mym = fmaxf(mym, __shfl_xor(mym, s));
  float myden = 0.f;
  for (int i = l; i < deg; i += 64) myden += __expf(logits_s[r0+i] - mym);
  #pragma unroll
  for (int s = 32; s; s >>= 1) myden += __shfl_xor(myden, s);
  const float inv = 1.f/(myden + 1e-8f);
  float acc0 = 0.f, acc1 = 0.f;
  for (int c0 = 0; c0 < deg; c0 += 64){
    const int len = min(64, deg - c0);
    float ex = 0.f;
    if (l < len) ex = __expf(logits_s[r0+c0+l] - mym);
    for (int j0 = 0; j0 < len; j0 += 4){
      const int jn = len - j0;
      const float* base = msgs + (size_t)(r0+c0+j0)*80;
      float v0=0,v1=0,v2=0,v3=0, w0=0,w1=0,w2=0,w3=0;
      float a0_=0,a1_=0,a2_=0,a3_=0;
      v0 = base[l]; if (l < 16) w0 = base[64+l]; a0_ = __shfl(ex, j0);
      if (jn > 1){ v1 = base[80+l];  if (l < 16) w1 = base[144+l]; a1_ = __shfl(ex, j0+1); }
      if (jn > 2){ v2 = base[160+l]; if (l < 16) w2 = base[224+l]; a2_ = __shfl(ex, j0+2); }
      if (jn > 3){ v3 = base[240+l]; if (l < 16) w3 = base[304+l]; a3_ = __shfl(ex, j0+3); }
      acc0 += a0_*v0 + a1_*v1 + a2_*v2 + a3_*v3;
      if (l < 16) acc1 += a0_*w0 + a1_*w1 + a2_*w2 + a3_*w3;
    }
  }
  aggl[wv][l] = acc0 * inv;
  if (l < 16) aggl[wv][64+l] = acc1 * inv;
  __syncthreads();

  const float* arow = &aggl[wv][0];
  const float iS = 0.17677669529663687f;  // 1/sqrt(32)
  const float iV = 0.25f;                 // 1/sqrt(16)
  for (int o = l; o < 80; o += 64){
    float val = 0.f;
    if (o < 32){
      for (int s = 0; s < 32; ++s) val += arow[s]*Wout_s[s*32+o];
      val *= iS;
    } else {
      int w = (o-32)/3, c = (o-32)-w*3;
      for (int v = 0; v < 16; ++v) val += arow[32+v*3+c]*Wout_v[v*16+w];
      val *= iV;
    }
    t1[wv][o] = val;
  }
  __syncthreads();
  for (int o = l; o < 96; o += 64){
    float val = 0.f;
    if (o < 48){
      for (int k = 0; k < 32; ++k) val += t1[wv][k]*Wg_s[k*48+o];
      val *= iS;
    } else {
      int w = (o-48)/3, c = (o-48)-w*3;
      for (int v = 0; v < 16; ++v) val += t1[wv][32+v*3+c]*Wg_v[v*16+w];
      val *= iV;
    }
    t2[wv][o] = val;
  }
  __syncthreads();
  for (int o = l; o < 80; o += 64){
    float x;
    if (o < 32){
      x = silu_f(t2[wv][o]) + nf[(size_t)nc*80+o];
      if (act){
        xbuf[(size_t)n*80+o] = x;
        atomicAdd(&bnl[o], x);
        atomicAdd(&bnl[32+o], x*x);
      }
    } else {
      int w = (o-32)/3;
      x = sigm_f(t2[wv][32+w]) * t2[wv][48+(o-32)] + nf[(size_t)nc*80+o];
      if (act){
        xbuf[(size_t)n*80+o] = x;
        atomicAdd(&bnl[64+w], x*x);
      }
    }
  }
  __syncthreads();
  if (t < 80) atomicAdd(&bnacc[t], bnl[t]);
}

// BN coef computed per-block (cheap), then normalize+affine
__global__ void __launch_bounds__(256) k_out(const float* __restrict__ xbuf,
    const float* __restrict__ bnacc,
    const float* __restrict__ bn_ws, const float* __restrict__ bn_bs,
    const float* __restrict__ bn_wv, float* __restrict__ out, int N){
  __shared__ float coef[80];
  int t = threadIdx.x;
  float fN = (float)N;
  if (t < 32){
    float mean = bnacc[t]/fN;
    float var = bnacc[32+t]/fN - mean*mean;
    float cm = bn_ws[t]*rsqrtf(var + 1e-5f);
    coef[t] = cm;
    coef[32+t] = bn_bs[t] - mean*cm;
  } else if (t < 48){
    int v = t - 32;
    coef[64+v] = bn_wv[v]*rsqrtf(bnacc[64+v]/(3.f*fN) + 1e-5f);
  }
  __syncthreads();
  int i = blockIdx.x*256 + t;
  if (i >= N*80) return;
  int o = i - (i/80)*80;
  float x = xbuf[i];
  out[i] = (o < 32) ? (x*coef[o] + coef[32+o]) : (x*coef[64+(o-32)/3]);
}

extern "C" void kernel_launch(void* const* d_in, const int* in_sizes, int n_in,
                              void* d_out, int out_size, void* d_ws, size_t ws_size,
                              hipStream_t stream) {
  const float* nf     = (const float*)d_in[0];
  const int*   ei     = (const int*)  d_in[1];
  const float* sh     = (const float*)d_in[2];
  const float* radial = (const float*)d_in[3];
  const float* env    = (const float*)d_in[4];
  const float* W1     = (const float*)d_in[5];
  const float* b1     = (const float*)d_in[6];
  const float* W2     = (const float*)d_in[7];
  const float* b2     = (const float*)d_in[8];
  const float* Wq     = (const float*)d_in[9];
  const float* bq     = (const float*)d_in[10];
  const float* Wk     = (const float*)d_in[11];
  const float* bk     = (const float*)d_in[12];
  const float* Wout_s = (const float*)d_in[13];
  const float* Wout_v = (const float*)d_in[14];
  const float* Wg_s   = (const float*)d_in[15];
  const float* Wg_v   = (const float*)d_in[16];
  const float* bn_ws  = (const float*)d_in[17];
  const float* bn_bs  = (const float*)d_in[18];
  const float* bn_wv  = (const float*)d_in[19];

  const int E = in_sizes[4];
  const int N = in_sizes[0] / 80;

  float* ws = (float*)d_ws;
  size_t off = 0;
  __bf16* w2t    = (__bf16*)(ws + off); off += 81920;   // [2][2560][32] bf16
  float* msgs    = ws + off; off += (size_t)E*80;
  float* logits_s= ws + off; off += E;
  int* cnt       = (int*)(ws + off); off += N;
  int* rowp      = (int*)(ws + off); off += N+1;
  int* cursor    = (int*)(ws + off); off += N;
  float* xbuf    = ws + off; off += (size_t)N*80;
  float* bnacc   = ws + off; off += 80;

  hipMemsetAsync(cnt, 0, (size_t)N*sizeof(int), stream);
  hipMemsetAsync(bnacc, 0, 80*sizeof(float), stream);

  const int nbPrep = 640;                 // 163840/256
  const int nbHist = (E + 255)/256;
  k_setup<<<nbPrep + nbHist, 256, 0, stream>>>(W2, w2t, ei, cnt, nbPrep, E);
  k_scan<<<1, 1024, 0, stream>>>(cnt, rowp, cursor, N, E);
  k_edge<<<(E + 15)/16, 256, 0, stream>>>(nf, ei, sh, radial, env,
      W1, b1, w2t, b2, Wq, bq, Wk, bk, cursor, msgs, logits_s, E);
  k_agg<<<(N + 3)/4, 256, 0, stream>>>(msgs, logits_s, rowp, nf,
      Wout_s, Wout_v, Wg_s, Wg_v, xbuf, bnacc, N);
  k_out<<<(N*80 + 255)/256, 256, 0, stream>>>(xbuf, bnacc, bn_ws, bn_bs, bn_wv,
      (float*)d_out, N);
}

// Round 12
// 410.098 us; speedup vs baseline: 1.0504x; 1.0504x over previous
//
#include <hip/hip_runtime.h>
#include <math.h>

typedef __bf16 bf16x8 __attribute__((ext_vector_type(8)));
typedef __bf16 bf16x4 __attribute__((ext_vector_type(4)));
typedef float  f32x4  __attribute__((ext_vector_type(4)));

__device__ __forceinline__ float silu_f(float x){ return x / (1.f + __expf(-x)); }
__device__ __forceinline__ float sigm_f(float x){ return 1.f / (1.f + __expf(-x)); }

__device__ __forceinline__ void fma4accb(float* acc, bf16x4 c, f32x4 d, float b){
  acc[0] += (float)c[0]*(d[0]+b); acc[1] += (float)c[1]*(d[1]+b);
  acc[2] += (float)c[2]*(d[2]+b); acc[3] += (float)c[3]*(d[3]+b);
}

// Block ranges: [0,nbPrep) W2->bf16 transpose; [nbPrep,+nbHist) dst histogram;
// rest: per-node attention vectors kv[n]=Wk@(nf@Wq+bq), c[n]=(nf@Wq+bq).bk
__global__ void __launch_bounds__(256) k_setup(const float* __restrict__ W2,
    __bf16* __restrict__ W2t, const int* __restrict__ ei, int* __restrict__ cnt,
    const float* __restrict__ nf, const float* __restrict__ Wq,
    const float* __restrict__ bq, const float* __restrict__ Wk,
    const float* __restrict__ bk, float* __restrict__ kvt, float* __restrict__ carr,
    int nbPrep, int nbHist, int N, int E){
  int b = blockIdx.x, t = threadIdx.x;
  if (b < nbPrep){
    int gid = b*256 + t;   // 163840 total
    int h = gid / 2560;
    int col = gid - h*2560;
    W2t[(size_t)(h>>5)*81920 + col*32 + (h&31)] = (__bf16)W2[gid];
    return;
  }
  if (b < nbPrep + nbHist){
    int e = (b - nbPrep)*256 + t;
    if (e < E) atomicAdd(&cnt[ei[E+e]], 1);
    return;
  }
  // kv/c blocks: 64 nodes each
  __shared__ float M[32][33];
  __shared__ float mb[32];
  __shared__ float nfl[64][33];
  __shared__ float bqbk_s;
  const int n0 = (b - nbPrep - nbHist)*64;
  for (int idx = t; idx < 1024; idx += 256){
    int s = idx >> 5, i = idx & 31;
    float acc = 0.f;
    #pragma unroll
    for (int j = 0; j < 8; ++j) acc += Wq[s*8+j]*Wk[i*8+j];
    M[s][i] = acc;
  }
  if (t < 32){
    float acc = 0.f;
    #pragma unroll
    for (int j = 0; j < 8; ++j) acc += Wq[t*8+j]*bk[j];
    mb[t] = acc;
  }
  if (t == 0){
    float acc = 0.f;
    #pragma unroll
    for (int j = 0; j < 8; ++j) acc += bq[j]*bk[j];
    bqbk_s = acc;
  }
  for (int idx = t; idx < 2048; idx += 256){
    int nl = idx >> 5, s = idx & 31;
    int n = n0 + nl;
    nfl[nl][s] = (n < N) ? nf[(size_t)n*80 + s] : 0.f;
  }
  __syncthreads();
  for (int idx = t; idx < 2048; idx += 256){
    int nl = idx >> 5, i = idx & 31;
    int n = n0 + nl;
    if (n < N){
      float acc = 0.f;
      #pragma unroll 8
      for (int s = 0; s < 32; ++s) acc += nfl[nl][s]*M[s][i];
      kvt[(size_t)n*32 + i] = acc;
    }
  }
  if (t < 64){
    int n = n0 + t;
    if (n < N){
      float acc = bqbk_s;
      #pragma unroll 8
      for (int s = 0; s < 32; ++s) acc += nfl[t][s]*mb[s];
      carr[n] = acc;
    }
  }
}

__global__ void __launch_bounds__(1024) k_scan(const int* __restrict__ cnt,
    int* __restrict__ rowp, int* __restrict__ cursor, float* __restrict__ bnacc,
    int N, int E){
  __shared__ int part[1024];
  int t = threadIdx.x;
  if (t < 80) bnacc[t] = 0.f;
  int chunk = (N + 1023) >> 10;
  int lo = t*chunk, hi = min(lo+chunk, N);
  int s = 0;
  for (int i = lo; i < hi; ++i) s += cnt[i];
  part[t] = s;
  __syncthreads();
  for (int off = 1; off < 1024; off <<= 1){
    int v = (t >= off) ? part[t-off] : 0;
    __syncthreads();
    part[t] += v;
    __syncthreads();
  }
  int base = (t == 0) ? 0 : part[t-1];
  for (int i = lo; i < hi; ++i){
    rowp[i] = base; cursor[i] = base;
    base += cnt[i];
  }
  if (t == 1023) rowp[N] = E;
}

// 16 edges / 256-thread block (R10 config), bf16 coef tables (8 blocks/CU),
// wave-specialized col ranges, depth-1 B+b2 prefetch, CSR placement fused,
// logits via precomputed per-node kv/c (4 FMA + 3 shfl per lane).
__global__ void __launch_bounds__(256) k_edge(
    const float* __restrict__ nf, const int* __restrict__ ei,
    const float* __restrict__ sh, const float* __restrict__ radial,
    const float* __restrict__ env,
    const float* __restrict__ W1, const float* __restrict__ b1,
    const __bf16* __restrict__ W2t, const float* __restrict__ b2,
    const float* __restrict__ kvt, const float* __restrict__ carr,
    int* __restrict__ cursor,
    float* __restrict__ msgs, float* __restrict__ logits_s, int E)
{
  __shared__ __bf16 u_lds[16][72];                 // 2304 B
  __shared__ float uniA[1360];                     // featT[80][17] <-> macc[16][84]
  __shared__ __bf16 cABt[48][20];                  // 1920 B
  __shared__ __align__(16) char uniB[7680];        // w1l f32[1024] <-> cVt bf16[64][3][20]
  __shared__ float shlT[4][17];
  __shared__ float radl[16][17];
  __shared__ float b1l[64];
  __shared__ int   src_l[16], dst_l[16], perm_l[16];

  float (*featT)[17] = (float(*)[17])uniA;
  float (*macc)[84]  = (float(*)[84])uniA;
  float* w1l = (float*)uniB;
  __bf16 (*cVt)[3][20] = (__bf16(*)[3][20])uniB;

  const int t = threadIdx.x;
  const int e0 = blockIdx.x*16;

  // ---- stage 1: indices + fused CSR placement, sh, radial, W1, b1
  if (t < 16){
    int ee = e0 + t;
    if (ee < E){
      int sn = ei[ee], dn = ei[E+ee];
      src_l[t] = sn; dst_l[t] = dn;
      perm_l[t] = atomicAdd(&cursor[dn], 1);
    } else {
      int ec = E-1;
      src_l[t] = ei[ec]; dst_l[t] = ei[E+ec]; perm_l[t] = 0;
    }
  }
  if (t >= 64 && t < 128){
    int i = t-64; int e = i>>2, c = i&3;
    int ec = min(e0+e, E-1);
    shlT[c][e] = sh[(size_t)ec*4+c];
  }
  if (t >= 128 && t < 192) b1l[t-128] = b1[t-128];
  {
    int e = t>>4, r = t&15;
    int ec = min(e0+e, E-1);
    radl[e][r] = radial[(size_t)ec*16+r];
  }
  *(float4*)&w1l[t*4] = ((const float4*)W1)[t];
  __syncthreads();

  // ---- stage 2: featT (transposed) + u = silu(radial@W1+b1) -> bf16
  for (int i = t; i < 1280; i += 256){
    int e = i / 80, idx = i - e*80;
    featT[idx][e] = nf[(size_t)src_l[e]*80 + idx];
  }
  for (int i = t; i < 1024; i += 256){
    int e = i & 15, h = i >> 4;
    float acc = b1l[h];
    #pragma unroll
    for (int r = 0; r < 16; ++r) acc += radl[e][r]*w1l[r*64+h];
    u_lds[e][h] = (__bf16)silu_f(acc);
  }
  __syncthreads();

  const float inv_s3 = 0.57735026918962576f;
  const float inv_s2 = 0.70710678118654752f;
  const float a0 = 0.14433756729740643f;  // 1/sqrt(48)
  const float a1 = 0.125f;                // 1/sqrt(64)

  // ---- stage 3: coefficients (bf16, transposed); cVt overwrites dead w1l
  for (int i = t; i < 768; i += 256){
    int r = i >> 4, e = i & 15;
    float val;
    if (r < 32) val = a0 * shlT[0][e] * featT[r][e];
    else {
      int v = r - 32;
      float dot = (featT[32+v*3][e]*shlT[1][e] + featT[33+v*3][e]*shlT[2][e]
                 + featT[34+v*3][e]*shlT[3][e]) * inv_s3;
      val = a0 * dot;
    }
    cABt[r][e] = (__bf16)val;
  }
  __syncthreads();   // all w1l reads done before cVt overwrite
  for (int i = t; i < 3072; i += 256){
    int e = i & 15, r = (i >> 4) & 63, c = i >> 10;
    float val;
    if (r < 32) val = a1 * shlT[1+c][e] * featT[r][e];
    else if (r < 48){
      int v = r - 32;
      val = a1 * shlT[0][e] * featT[32+v*3+c][e];
    } else {
      int v = r - 48;
      int c1 = c+1; if (c1 > 2) c1 -= 3;
      int c2 = c+2; if (c2 > 2) c2 -= 3;
      val = a1 * inv_s2 * (featT[32+v*3+c1][e]*shlT[1+c2][e]
                         - featT[32+v*3+c2][e]*shlT[1+c1][e]);
    }
    cVt[r][c][e] = (__bf16)val;
  }
  __syncthreads();

  // ---- zero macc (aliases featT, now dead)
  for (int i = t; i < 1344; i += 256) uniA[i] = 0.f;
  __syncthreads();

  // ---- stage 4: MFMA tile loop, wave-specialized, 1-deep prefetch
  const int lane = t & 63;
  const int wv   = t >> 6;
  const int quad = lane >> 4;
  const int nlo  = lane & 15;

  bf16x8 afr0 = *(const bf16x8*)&u_lds[nlo][quad*8];
  bf16x8 afr1 = *(const bf16x8*)&u_lds[nlo][32 + quad*8];

  const bool scalarW = (wv < 2);
  const int itBeg = scalarW ? wv*48 : 96 + (wv-2)*32;
  const int itEnd = scalarW ? itBeg + 48 : itBeg + 32;

  float accS0[4] = {0,0,0,0};
  float accS1[4] = {0,0,0,0};
  float accV0[4] = {0,0,0,0};
  float accV1[4] = {0,0,0,0};
  float accV2[4] = {0,0,0,0};

  const __bf16* bpBase = W2t + (size_t)nlo*32 + (size_t)quad*8;
  bf16x8 cb0 = *(const bf16x8*)(bpBase + (size_t)itBeg*512);
  bf16x8 cb1 = *(const bf16x8*)(bpBase + (size_t)itBeg*512 + 81920);
  float  cbc = b2[itBeg*16 + nlo];

  for (int it = itBeg; it < itEnd; ++it){
    bf16x8 nb0 = cb0, nb1 = cb1; float nbc = cbc;
    if (it + 1 < itEnd){
      const __bf16* bp = bpBase + (size_t)(it+1)*512;
      nb0 = *(const bf16x8*)(bp);
      nb1 = *(const bf16x8*)(bp + 81920);
      nbc = b2[(it+1)*16 + nlo];
    }
    f32x4 d = {0.f,0.f,0.f,0.f};
    d = __builtin_amdgcn_mfma_f32_16x16x32_bf16(afr0, cb0, d, 0, 0, 0);
    d = __builtin_amdgcn_mfma_f32_16x16x32_bf16(afr1, cb1, d, 0, 0, 0);
    if (scalarW){
      const int r = it >> 1;
      const bf16x4 c4 = *(const bf16x4*)&cABt[r][quad*4];
      if (it & 1) fma4accb(accS1, c4, d, cbc);
      else        fma4accb(accS0, c4, d, cbc);
    } else {
      const int r = it - 96;
      const bf16x4 v0 = *(const bf16x4*)&cVt[r][0][quad*4];
      const bf16x4 v1 = *(const bf16x4*)&cVt[r][1][quad*4];
      const bf16x4 v2 = *(const bf16x4*)&cVt[r][2][quad*4];
      fma4accb(accV0, v0, d, cbc);
      fma4accb(accV1, v1, d, cbc);
      fma4accb(accV2, v2, d, cbc);
    }
    cb0 = nb0; cb1 = nb1; cbc = nbc;
  }

  // ---- cross-wave reduce into macc
  if (scalarW){
    #pragma unroll
    for (int reg = 0; reg < 4; ++reg){
      const int m = quad*4+reg;
      atomicAdd(&macc[m][nlo],    accS0[reg]);
      atomicAdd(&macc[m][16+nlo], accS1[reg]);
    }
  } else {
    #pragma unroll
    for (int reg = 0; reg < 4; ++reg){
      const int m = quad*4+reg;
      atomicAdd(&macc[m][32+nlo*3+0], accV0[reg]);
      atomicAdd(&macc[m][32+nlo*3+1], accV1[reg]);
      atomicAdd(&macc[m][32+nlo*3+2], accV2[reg]);
    }
  }
  __syncthreads();

  // ---- logits (waves 0-1): logit = (msg_s . kv[dst] + c[dst]) / sqrt(8) + log(env)
  if (t < 128){
    const int l = t & 63;
    const int e = (t >> 6)*8 + (l >> 3);
    const int kq = l & 7;
    const int eg = e0 + e;
    float4 ms = *(const float4*)&macc[e][kq*4];
    int dn = dst_l[e];
    const float* kvp = kvt + (size_t)dn*32 + kq*4;
    float part = ms.x*kvp[0] + ms.y*kvp[1] + ms.z*kvp[2] + ms.w*kvp[3];
    part += __shfl_xor(part, 1);
    part += __shfl_xor(part, 2);
    part += __shfl_xor(part, 4);
    if (kq == 0 && eg < E){
      float lg = (part + carr[dn]) * 0.35355339059327373f + logf(env[eg] + 1e-8f);
      logits_s[perm_l[e]] = lg;
    }
  }

  // ---- store messages in CSR order
  for (int i = t; i < 320; i += 256){
    int e = i/20, r = i - (i/20)*20;
    if (e0 + e < E)
      ((float4*)(msgs + (size_t)perm_l[e]*80))[r] = *(const float4*)&macc[e][r*4];
  }
}

// One wave per node: max pass, then single merged pass accumulating
// unnormalized sum(ex*msg) and den simultaneously; fused node matmuls +
// gate + residual + BN stats.
__global__ void __launch_bounds__(256) k_agg(
    const float* __restrict__ msgs, const float* __restrict__ logits_s,
    const int* __restrict__ rowp, const float* __restrict__ nf,
    const float* __restrict__ Wout_s, const float* __restrict__ Wout_v,
    const float* __restrict__ Wg_s, const float* __restrict__ Wg_v,
    float* __restrict__ xbuf, float* __restrict__ bnacc, int N)
{
  __shared__ float aggl[4][80];
  __shared__ float t1[4][96];
  __shared__ float t2[4][96];
  __shared__ float bnl[80];
  const int t = threadIdx.x, l = t & 63, wv = t >> 6;
  const int n = blockIdx.x*4 + wv;
  const bool act = (n < N);
  const int nc = act ? n : (N-1);
  if (t < 80) bnl[t] = 0.f;

  const int r0 = rowp[nc], r1 = rowp[nc+1];
  const int deg = act ? (r1 - r0) : 0;

  // pass 1: max logit
  float mym = -3.4e38f;
  for (int i = l; i < deg; i += 64) mym = fmaxf(mym, logits_s[r0+i]);
  #pragma unroll
  for (int s = 32; s; s >>= 1) mym = fmaxf(mym, __shfl_xor(mym, s));
  // pass 2 (merged): unnormalized gather + den
  float denp = 0.f, acc0 = 0.f, acc1 = 0.f;
  for (int c0 = 0; c0 < deg; c0 += 64){
    const int len = min(64, deg - c0);
    float ex = 0.f;
    if (l < len) ex = __expf(logits_s[r0+c0+l] - mym);
    denp += ex;
    for (int j0 = 0; j0 < len; j0 += 4){
      const int jn = len - j0;
      const float* base = msgs + (size_t)(r0+c0+j0)*80;
      float v0=0,v1=0,v2=0,v3=0, w0=0,w1=0,w2=0,w3=0;
      float a0_=0,a1_=0,a2_=0,a3_=0;
      v0 = base[l]; if (l < 16) w0 = base[64+l]; a0_ = __shfl(ex, j0);
      if (jn > 1){ v1 = base[80+l];  if (l < 16) w1 = base[144+l]; a1_ = __shfl(ex, j0+1); }
      if (jn > 2){ v2 = base[160+l]; if (l < 16) w2 = base[224+l]; a2_ = __shfl(ex, j0+2); }
      if (jn > 3){ v3 = base[240+l]; if (l < 16) w3 = base[304+l]; a3_ = __shfl(ex, j0+3); }
      acc0 += a0_*v0 + a1_*v1 + a2_*v2 + a3_*v3;
      if (l < 16) acc1 += a0_*w0 + a1_*w1 + a2_*w2 + a3_*w3;
    }
  }
  #pragma unroll
  for (int s = 32; s; s >>= 1) denp += __shfl_xor(denp, s);
  const float inv = 1.f/(denp + 1e-8f);
  aggl[wv][l] = acc0 * inv;
  if (l < 16) aggl[wv][64+l] = acc1 * inv;
  __syncthreads();

  const float* arow = &aggl[wv][0];
  const float iS = 0.17677669529663687f;  // 1/sqrt(32)
  const float iV = 0.25f;                 // 1/sqrt(16)
  for (int o = l; o < 80; o += 64){
    float val = 0.f;
    if (o < 32){
      for (int s = 0; s < 32; ++s) val += arow[s]*Wout_s[s*32+o];
      val *= iS;
    } else {
      int w = (o-32)/3, c = (o-32)-w*3;
      for (int v = 0; v < 16; ++v) val += arow[32+v*3+c]*Wout_v[v*16+w];
      val *= iV;
    }
    t1[wv][o] = val;
  }
  __syncthreads();
  for (int o = l; o < 96; o += 64){
    float val = 0.f;
    if (o < 48){
      for (int k = 0; k < 32; ++k) val += t1[wv][k]*Wg_s[k*48+o];
      val *= iS;
    } else {
      int w = (o-48)/3, c = (o-48)-w*3;
      for (int v = 0; v < 16; ++v) val += t1[wv][32+v*3+c]*Wg_v[v*16+w];
      val *= iV;
    }
    t2[wv][o] = val;
  }
  __syncthreads();
  for (int o = l; o < 80; o += 64){
    float x;
    if (o < 32){
      x = silu_f(t2[wv][o]) + nf[(size_t)nc*80+o];
      if (act){
        xbuf[(size_t)n*80+o] = x;
        atomicAdd(&bnl[o], x);
        atomicAdd(&bnl[32+o], x*x);
      }
    } else {
      int w = (o-32)/3;
      x = sigm_f(t2[wv][32+w]) * t2[wv][48+(o-32)] + nf[(size_t)nc*80+o];
      if (act){
        xbuf[(size_t)n*80+o] = x;
        atomicAdd(&bnl[64+w], x*x);
      }
    }
  }
  __syncthreads();
  if (t < 80) atomicAdd(&bnacc[t], bnl[t]);
}

// BN coef computed per-block (cheap), then normalize+affine
__global__ void __launch_bounds__(256) k_out(const float* __restrict__ xbuf,
    const float* __restrict__ bnacc,
    const float* __restrict__ bn_ws, const float* __restrict__ bn_bs,
    const float* __restrict__ bn_wv, float* __restrict__ out, int N){
  __shared__ float coef[80];
  int t = threadIdx.x;
  float fN = (float)N;
  if (t < 32){
    float mean = bnacc[t]/fN;
    float var = bnacc[32+t]/fN - mean*mean;
    float cm = bn_ws[t]*rsqrtf(var + 1e-5f);
    coef[t] = cm;
    coef[32+t] = bn_bs[t] - mean*cm;
  } else if (t < 48){
    int v = t - 32;
    coef[64+v] = bn_wv[v]*rsqrtf(bnacc[64+v]/(3.f*fN) + 1e-5f);
  }
  __syncthreads();
  int i = blockIdx.x*256 + t;
  if (i >= N*80) return;
  int o = i - (i/80)*80;
  float x = xbuf[i];
  out[i] = (o < 32) ? (x*coef[o] + coef[32+o]) : (x*coef[64+(o-32)/3]);
}

extern "C" void kernel_launch(void* const* d_in, const int* in_sizes, int n_in,
                              void* d_out, int out_size, void* d_ws, size_t ws_size,
                              hipStream_t stream) {
  const float* nf     = (const float*)d_in[0];
  const int*   ei     = (const int*)  d_in[1];
  const float* sh     = (const float*)d_in[2];
  const float* radial = (const float*)d_in[3];
  const float* env    = (const float*)d_in[4];
  const float* W1     = (const float*)d_in[5];
  const float* b1     = (const float*)d_in[6];
  const float* W2     = (const float*)d_in[7];
  const float* b2     = (const float*)d_in[8];
  const float* Wq     = (const float*)d_in[9];
  const float* bq     = (const float*)d_in[10];
  const float* Wk     = (const float*)d_in[11];
  const float* bk     = (const float*)d_in[12];
  const float* Wout_s = (const float*)d_in[13];
  const float* Wout_v = (const float*)d_in[14];
  const float* Wg_s   = (const float*)d_in[15];
  const float* Wg_v   = (const float*)d_in[16];
  const float* bn_ws  = (const float*)d_in[17];
  const float* bn_bs  = (const float*)d_in[18];
  const float* bn_wv  = (const float*)d_in[19];

  const int E = in_sizes[4];
  const int N = in_sizes[0] / 80;

  float* ws = (float*)d_ws;
  size_t off = 0;
  __bf16* w2t    = (__bf16*)(ws + off); off += 81920;   // [2][2560][32] bf16
  float* msgs    = ws + off; off += (size_t)E*80;
  float* logits_s= ws + off; off += E;
  int* cnt       = (int*)(ws + off); off += N;
  int* rowp      = (int*)(ws + off); off += N+1;
  int* cursor    = (int*)(ws + off); off += N;
  float* xbuf    = ws + off; off += (size_t)N*80;
  float* bnacc   = ws + off; off += 80;
  float* kvt     = ws + off; off += (size_t)N*32;
  float* carr    = ws + off; off += N;

  hipMemsetAsync(cnt, 0, (size_t)N*sizeof(int), stream);

  const int nbPrep = 640;                 // 163840/256
  const int nbHist = (E + 255)/256;
  const int nbKv   = (N + 63)/64;
  k_setup<<<nbPrep + nbHist + nbKv, 256, 0, stream>>>(W2, w2t, ei, cnt,
      nf, Wq, bq, Wk, bk, kvt, carr, nbPrep, nbHist, N, E);
  k_scan<<<1, 1024, 0, stream>>>(cnt, rowp, cursor, bnacc, N, E);
  k_edge<<<(E + 15)/16, 256, 0, stream>>>(nf, ei, sh, radial, env,
      W1, b1, w2t, b2, kvt, carr, cursor, msgs, logits_s, E);
  k_agg<<<(N + 3)/4, 256, 0, stream>>>(msgs, logits_s, rowp, nf,
      Wout_s, Wout_v, Wg_s, Wg_v, xbuf, bnacc, N);
  k_out<<<(N*80 + 255)/256, 256, 0, stream>>>(xbuf, bnacc, bn_ws, bn_bs, bn_wv,
      (float*)d_out, N);
}

// Round 13
// 396.972 us; speedup vs baseline: 1.0851x; 1.0331x over previous
//
#include <hip/hip_runtime.h>
#include <math.h>

typedef __bf16 bf16x8 __attribute__((ext_vector_type(8)));
typedef __bf16 bf16x4 __attribute__((ext_vector_type(4)));
typedef float  f32x4  __attribute__((ext_vector_type(4)));

__device__ __forceinline__ float silu_f(float x){ return x / (1.f + __expf(-x)); }
__device__ __forceinline__ float sigm_f(float x){ return 1.f / (1.f + __expf(-x)); }

__device__ __forceinline__ void fma4accb(float* acc, bf16x4 c, f32x4 d, float b){
  acc[0] += (float)c[0]*(d[0]+b); acc[1] += (float)c[1]*(d[1]+b);
  acc[2] += (float)c[2]*(d[2]+b); acc[3] += (float)c[3]*(d[3]+b);
}

// Block ranges: [0,nbPrep) W2->bf16 transpose; [nbPrep,+nbHist) dst histogram;
// rest: per-node attention vectors kv[n]=Wk@(nf@Wq+bq), c[n]=(nf@Wq+bq).bk
__global__ void __launch_bounds__(256) k_setup(const float* __restrict__ W2,
    __bf16* __restrict__ W2t, const int* __restrict__ ei, int* __restrict__ cnt,
    const float* __restrict__ nf, const float* __restrict__ Wq,
    const float* __restrict__ bq, const float* __restrict__ Wk,
    const float* __restrict__ bk, float* __restrict__ kvt, float* __restrict__ carr,
    int nbPrep, int nbHist, int N, int E){
  int b = blockIdx.x, t = threadIdx.x;
  if (b < nbPrep){
    int gid = b*256 + t;   // 163840 total
    int h = gid / 2560;
    int col = gid - h*2560;
    W2t[(size_t)(h>>5)*81920 + col*32 + (h&31)] = (__bf16)W2[gid];
    return;
  }
  if (b < nbPrep + nbHist){
    int e = (b - nbPrep)*256 + t;
    if (e < E) atomicAdd(&cnt[ei[E+e]], 1);
    return;
  }
  // kv/c blocks: 64 nodes each
  __shared__ float M[32][33];
  __shared__ float mb[32];
  __shared__ float nfl[64][33];
  __shared__ float bqbk_s;
  const int n0 = (b - nbPrep - nbHist)*64;
  for (int idx = t; idx < 1024; idx += 256){
    int s = idx >> 5, i = idx & 31;
    float acc = 0.f;
    #pragma unroll
    for (int j = 0; j < 8; ++j) acc += Wq[s*8+j]*Wk[i*8+j];
    M[s][i] = acc;
  }
  if (t < 32){
    float acc = 0.f;
    #pragma unroll
    for (int j = 0; j < 8; ++j) acc += Wq[t*8+j]*bk[j];
    mb[t] = acc;
  }
  if (t == 0){
    float acc = 0.f;
    #pragma unroll
    for (int j = 0; j < 8; ++j) acc += bq[j]*bk[j];
    bqbk_s = acc;
  }
  for (int idx = t; idx < 2048; idx += 256){
    int nl = idx >> 5, s = idx & 31;
    int n = n0 + nl;
    nfl[nl][s] = (n < N) ? nf[(size_t)n*80 + s] : 0.f;
  }
  __syncthreads();
  for (int idx = t; idx < 2048; idx += 256){
    int nl = idx >> 5, i = idx & 31;
    int n = n0 + nl;
    if (n < N){
      float acc = 0.f;
      #pragma unroll 8
      for (int s = 0; s < 32; ++s) acc += nfl[nl][s]*M[s][i];
      kvt[(size_t)n*32 + i] = acc;
    }
  }
  if (t < 64){
    int n = n0 + t;
    if (n < N){
      float acc = bqbk_s;
      #pragma unroll 8
      for (int s = 0; s < 32; ++s) acc += nfl[t][s]*mb[s];
      carr[n] = acc;
    }
  }
}

__global__ void __launch_bounds__(1024) k_scan(const int* __restrict__ cnt,
    int* __restrict__ cursor, float* __restrict__ bnacc, int N, int E){
  __shared__ int part[1024];
  int t = threadIdx.x;
  if (t < 80) bnacc[t] = 0.f;
  int chunk = (N + 1023) >> 10;
  int lo = t*chunk, hi = min(lo+chunk, N);
  int s = 0;
  for (int i = lo; i < hi; ++i) s += cnt[i];
  part[t] = s;
  __syncthreads();
  for (int off = 1; off < 1024; off <<= 1){
    int v = (t >= off) ? part[t-off] : 0;
    __syncthreads();
    part[t] += v;
    __syncthreads();
  }
  int base = (t == 0) ? 0 : part[t-1];
  for (int i = lo; i < hi; ++i){
    cursor[i] = base;
    base += cnt[i];
  }
}

// 16 edges / 256-thread block (R12 config), bf16 coef tables (8 blocks/CU),
// wave-specialized col ranges, depth-1 B+b2 prefetch, CSR placement fused,
// logits via precomputed per-node kv/c, msgs stored in bf16 (halved traffic).
__global__ void __launch_bounds__(256) k_edge(
    const float* __restrict__ nf, const int* __restrict__ ei,
    const float* __restrict__ sh, const float* __restrict__ radial,
    const float* __restrict__ env,
    const float* __restrict__ W1, const float* __restrict__ b1,
    const __bf16* __restrict__ W2t, const float* __restrict__ b2,
    const float* __restrict__ kvt, const float* __restrict__ carr,
    int* __restrict__ cursor,
    __bf16* __restrict__ msgs, float* __restrict__ logits_s, int E)
{
  __shared__ __bf16 u_lds[16][72];                 // 2304 B
  __shared__ float uniA[1360];                     // featT[80][17] <-> macc[16][84]
  __shared__ __bf16 cABt[48][20];                  // 1920 B
  __shared__ __align__(16) char uniB[7680];        // w1l f32[1024] <-> cVt bf16[64][3][20]
  __shared__ float shlT[4][17];
  __shared__ float radl[16][17];
  __shared__ float b1l[64];
  __shared__ int   src_l[16], dst_l[16], perm_l[16];

  float (*featT)[17] = (float(*)[17])uniA;
  float (*macc)[84]  = (float(*)[84])uniA;
  float* w1l = (float*)uniB;
  __bf16 (*cVt)[3][20] = (__bf16(*)[3][20])uniB;

  const int t = threadIdx.x;
  const int e0 = blockIdx.x*16;

  // ---- stage 1: indices + fused CSR placement, sh, radial, W1, b1
  if (t < 16){
    int ee = e0 + t;
    if (ee < E){
      int sn = ei[ee], dn = ei[E+ee];
      src_l[t] = sn; dst_l[t] = dn;
      perm_l[t] = atomicAdd(&cursor[dn], 1);
    } else {
      int ec = E-1;
      src_l[t] = ei[ec]; dst_l[t] = ei[E+ec]; perm_l[t] = 0;
    }
  }
  if (t >= 64 && t < 128){
    int i = t-64; int e = i>>2, c = i&3;
    int ec = min(e0+e, E-1);
    shlT[c][e] = sh[(size_t)ec*4+c];
  }
  if (t >= 128 && t < 192) b1l[t-128] = b1[t-128];
  {
    int e = t>>4, r = t&15;
    int ec = min(e0+e, E-1);
    radl[e][r] = radial[(size_t)ec*16+r];
  }
  *(float4*)&w1l[t*4] = ((const float4*)W1)[t];
  __syncthreads();

  // ---- stage 2: featT (transposed) + u = silu(radial@W1+b1) -> bf16
  for (int i = t; i < 1280; i += 256){
    int e = i / 80, idx = i - e*80;
    featT[idx][e] = nf[(size_t)src_l[e]*80 + idx];
  }
  for (int i = t; i < 1024; i += 256){
    int e = i & 15, h = i >> 4;
    float acc = b1l[h];
    #pragma unroll
    for (int r = 0; r < 16; ++r) acc += radl[e][r]*w1l[r*64+h];
    u_lds[e][h] = (__bf16)silu_f(acc);
  }
  __syncthreads();

  const float inv_s3 = 0.57735026918962576f;
  const float inv_s2 = 0.70710678118654752f;
  const float a0 = 0.14433756729740643f;  // 1/sqrt(48)
  const float a1 = 0.125f;                // 1/sqrt(64)

  // ---- stage 3: coefficients (bf16, transposed); cVt overwrites dead w1l
  for (int i = t; i < 768; i += 256){
    int r = i >> 4, e = i & 15;
    float val;
    if (r < 32) val = a0 * shlT[0][e] * featT[r][e];
    else {
      int v = r - 32;
      float dot = (featT[32+v*3][e]*shlT[1][e] + featT[33+v*3][e]*shlT[2][e]
                 + featT[34+v*3][e]*shlT[3][e]) * inv_s3;
      val = a0 * dot;
    }
    cABt[r][e] = (__bf16)val;
  }
  __syncthreads();   // all w1l reads done before cVt overwrite
  for (int i = t; i < 3072; i += 256){
    int e = i & 15, r = (i >> 4) & 63, c = i >> 10;
    float val;
    if (r < 32) val = a1 * shlT[1+c][e] * featT[r][e];
    else if (r < 48){
      int v = r - 32;
      val = a1 * shlT[0][e] * featT[32+v*3+c][e];
    } else {
      int v = r - 48;
      int c1 = c+1; if (c1 > 2) c1 -= 3;
      int c2 = c+2; if (c2 > 2) c2 -= 3;
      val = a1 * inv_s2 * (featT[32+v*3+c1][e]*shlT[1+c2][e]
                         - featT[32+v*3+c2][e]*shlT[1+c1][e]);
    }
    cVt[r][c][e] = (__bf16)val;
  }
  __syncthreads();

  // ---- zero macc (aliases featT, now dead)
  for (int i = t; i < 1344; i += 256) uniA[i] = 0.f;
  __syncthreads();

  // ---- stage 4: MFMA tile loop, wave-specialized, 1-deep prefetch
  const int lane = t & 63;
  const int wv   = t >> 6;
  const int quad = lane >> 4;
  const int nlo  = lane & 15;

  bf16x8 afr0 = *(const bf16x8*)&u_lds[nlo][quad*8];
  bf16x8 afr1 = *(const bf16x8*)&u_lds[nlo][32 + quad*8];

  const bool scalarW = (wv < 2);
  const int itBeg = scalarW ? wv*48 : 96 + (wv-2)*32;
  const int itEnd = scalarW ? itBeg + 48 : itBeg + 32;

  float accS0[4] = {0,0,0,0};
  float accS1[4] = {0,0,0,0};
  float accV0[4] = {0,0,0,0};
  float accV1[4] = {0,0,0,0};
  float accV2[4] = {0,0,0,0};

  const __bf16* bpBase = W2t + (size_t)nlo*32 + (size_t)quad*8;
  bf16x8 cb0 = *(const bf16x8*)(bpBase + (size_t)itBeg*512);
  bf16x8 cb1 = *(const bf16x8*)(bpBase + (size_t)itBeg*512 + 81920);
  float  cbc = b2[itBeg*16 + nlo];

  for (int it = itBeg; it < itEnd; ++it){
    bf16x8 nb0 = cb0, nb1 = cb1; float nbc = cbc;
    if (it + 1 < itEnd){
      const __bf16* bp = bpBase + (size_t)(it+1)*512;
      nb0 = *(const bf16x8*)(bp);
      nb1 = *(const bf16x8*)(bp + 81920);
      nbc = b2[(it+1)*16 + nlo];
    }
    f32x4 d = {0.f,0.f,0.f,0.f};
    d = __builtin_amdgcn_mfma_f32_16x16x32_bf16(afr0, cb0, d, 0, 0, 0);
    d = __builtin_amdgcn_mfma_f32_16x16x32_bf16(afr1, cb1, d, 0, 0, 0);
    if (scalarW){
      const int r = it >> 1;
      const bf16x4 c4 = *(const bf16x4*)&cABt[r][quad*4];
      if (it & 1) fma4accb(accS1, c4, d, cbc);
      else        fma4accb(accS0, c4, d, cbc);
    } else {
      const int r = it - 96;
      const bf16x4 v0 = *(const bf16x4*)&cVt[r][0][quad*4];
      const bf16x4 v1 = *(const bf16x4*)&cVt[r][1][quad*4];
      const bf16x4 v2 = *(const bf16x4*)&cVt[r][2][quad*4];
      fma4accb(accV0, v0, d, cbc);
      fma4accb(accV1, v1, d, cbc);
      fma4accb(accV2, v2, d, cbc);
    }
    cb0 = nb0; cb1 = nb1; cbc = nbc;
  }

  // ---- cross-wave reduce into macc
  if (scalarW){
    #pragma unroll
    for (int reg = 0; reg < 4; ++reg){
      const int m = quad*4+reg;
      atomicAdd(&macc[m][nlo],    accS0[reg]);
      atomicAdd(&macc[m][16+nlo], accS1[reg]);
    }
  } else {
    #pragma unroll
    for (int reg = 0; reg < 4; ++reg){
      const int m = quad*4+reg;
      atomicAdd(&macc[m][32+nlo*3+0], accV0[reg]);
      atomicAdd(&macc[m][32+nlo*3+1], accV1[reg]);
      atomicAdd(&macc[m][32+nlo*3+2], accV2[reg]);
    }
  }
  __syncthreads();

  // ---- logits (waves 0-1): logit = (msg_s . kv[dst] + c[dst]) / sqrt(8) + log(env)
  if (t < 128){
    const int l = t & 63;
    const int e = (t >> 6)*8 + (l >> 3);
    const int kq = l & 7;
    const int eg = e0 + e;
    float4 ms = *(const float4*)&macc[e][kq*4];
    int dn = dst_l[e];
    const float* kvp = kvt + (size_t)dn*32 + kq*4;
    float part = ms.x*kvp[0] + ms.y*kvp[1] + ms.z*kvp[2] + ms.w*kvp[3];
    part += __shfl_xor(part, 1);
    part += __shfl_xor(part, 2);
    part += __shfl_xor(part, 4);
    if (kq == 0 && eg < E){
      float lg = (part + carr[dn]) * 0.35355339059327373f + logf(env[eg] + 1e-8f);
      logits_s[perm_l[e]] = lg;
    }
  }

  // ---- store messages in CSR order (bf16)
  for (int i = t; i < 320; i += 256){
    int e = i/20, r = i - (i/20)*20;
    if (e0 + e < E){
      const float4 m4 = *(const float4*)&macc[e][r*4];
      bf16x4 b4; b4[0] = (__bf16)m4.x; b4[1] = (__bf16)m4.y;
                 b4[2] = (__bf16)m4.z; b4[3] = (__bf16)m4.w;
      ((bf16x4*)(msgs + (size_t)perm_l[e]*80))[r] = b4;
    }
  }
}

// One wave per node: max pass, merged gather+den pass (bf16 msgs), fused
// node matmuls + gate + residual + BN stats. CSR bounds from cursor array
// (cursor[n] == segment end after k_edge; start = cursor[n-1] or 0).
__global__ void __launch_bounds__(256) k_agg(
    const __bf16* __restrict__ msgs, const float* __restrict__ logits_s,
    const int* __restrict__ cursor, const float* __restrict__ nf,
    const float* __restrict__ Wout_s, const float* __restrict__ Wout_v,
    const float* __restrict__ Wg_s, const float* __restrict__ Wg_v,
    float* __restrict__ xbuf, float* __restrict__ bnacc, int N)
{
  __shared__ float aggl[4][80];
  __shared__ float t1[4][96];
  __shared__ float t2[4][96];
  __shared__ float bnl[80];
  const int t = threadIdx.x, l = t & 63, wv = t >> 6;
  const int n = blockIdx.x*4 + wv;
  const bool act = (n < N);
  const int nc = act ? n : (N-1);
  if (t < 80) bnl[t] = 0.f;

  const int r0 = (nc == 0) ? 0 : cursor[nc-1];
  const int r1 = cursor[nc];
  const int deg = act ? (r1 - r0) : 0;

  // pass 1: max logit
  float mym = -3.4e38f;
  for (int i = l; i < deg; i += 64) mym = fmaxf(mym, logits_s[r0+i]);
  #pragma unroll
  for (int s = 32; s; s >>= 1) mym = fmaxf(mym, __shfl_xor(mym, s));
  // pass 2 (merged): unnormalized gather + den
  float denp = 0.f, acc0 = 0.f, acc1 = 0.f;
  for (int c0 = 0; c0 < deg; c0 += 64){
    const int len = min(64, deg - c0);
    float ex = 0.f;
    if (l < len) ex = __expf(logits_s[r0+c0+l] - mym);
    denp += ex;
    for (int j0 = 0; j0 < len; j0 += 4){
      const int jn = len - j0;
      const __bf16* base = msgs + (size_t)(r0+c0+j0)*80;
      float v0=0,v1=0,v2=0,v3=0, w0=0,w1=0,w2=0,w3=0;
      float a0_=0,a1_=0,a2_=0,a3_=0;
      v0 = (float)base[l]; if (l < 16) w0 = (float)base[64+l]; a0_ = __shfl(ex, j0);
      if (jn > 1){ v1 = (float)base[80+l];  if (l < 16) w1 = (float)base[144+l]; a1_ = __shfl(ex, j0+1); }
      if (jn > 2){ v2 = (float)base[160+l]; if (l < 16) w2 = (float)base[224+l]; a2_ = __shfl(ex, j0+2); }
      if (jn > 3){ v3 = (float)base[240+l]; if (l < 16) w3 = (float)base[304+l]; a3_ = __shfl(ex, j0+3); }
      acc0 += a0_*v0 + a1_*v1 + a2_*v2 + a3_*v3;
      if (l < 16) acc1 += a0_*w0 + a1_*w1 + a2_*w2 + a3_*w3;
    }
  }
  #pragma unroll
  for (int s = 32; s; s >>= 1) denp += __shfl_xor(denp, s);
  const float inv = 1.f/(denp + 1e-8f);
  aggl[wv][l] = acc0 * inv;
  if (l < 16) aggl[wv][64+l] = acc1 * inv;
  __syncthreads();

  const float* arow = &aggl[wv][0];
  const float iS = 0.17677669529663687f;  // 1/sqrt(32)
  const float iV = 0.25f;                 // 1/sqrt(16)
  for (int o = l; o < 80; o += 64){
    float val = 0.f;
    if (o < 32){
      for (int s = 0; s < 32; ++s) val += arow[s]*Wout_s[s*32+o];
      val *= iS;
    } else {
      int w = (o-32)/3, c = (o-32)-w*3;
      for (int v = 0; v < 16; ++v) val += arow[32+v*3+c]*Wout_v[v*16+w];
      val *= iV;
    }
    t1[wv][o] = val;
  }
  __syncthreads();
  for (int o = l; o < 96; o += 64){
    float val = 0.f;
    if (o < 48){
      for (int k = 0; k < 32; ++k) val += t1[wv][k]*Wg_s[k*48+o];
      val *= iS;
    } else {
      int w = (o-48)/3, c = (o-48)-w*3;
      for (int v = 0; v < 16; ++v) val += t1[wv][32+v*3+c]*Wg_v[v*16+w];
      val *= iV;
    }
    t2[wv][o] = val;
  }
  __syncthreads();
  for (int o = l; o < 80; o += 64){
    float x;
    if (o < 32){
      x = silu_f(t2[wv][o]) + nf[(size_t)nc*80+o];
      if (act){
        xbuf[(size_t)n*80+o] = x;
        atomicAdd(&bnl[o], x);
        atomicAdd(&bnl[32+o], x*x);
      }
    } else {
      int w = (o-32)/3;
      x = sigm_f(t2[wv][32+w]) * t2[wv][48+(o-32)] + nf[(size_t)nc*80+o];
      if (act){
        xbuf[(size_t)n*80+o] = x;
        atomicAdd(&bnl[64+w], x*x);
      }
    }
  }
  __syncthreads();
  if (t < 80) atomicAdd(&bnacc[t], bnl[t]);
}

// BN coef computed per-block (cheap), then normalize+affine
__global__ void __launch_bounds__(256) k_out(const float* __restrict__ xbuf,
    const float* __restrict__ bnacc,
    const float* __restrict__ bn_ws, const float* __restrict__ bn_bs,
    const float* __restrict__ bn_wv, float* __restrict__ out, int N){
  __shared__ float coef[80];
  int t = threadIdx.x;
  float fN = (float)N;
  if (t < 32){
    float mean = bnacc[t]/fN;
    float var = bnacc[32+t]/fN - mean*mean;
    float cm = bn_ws[t]*rsqrtf(var + 1e-5f);
    coef[t] = cm;
    coef[32+t] = bn_bs[t] - mean*cm;
  } else if (t < 48){
    int v = t - 32;
    coef[64+v] = bn_wv[v]*rsqrtf(bnacc[64+v]/(3.f*fN) + 1e-5f);
  }
  __syncthreads();
  int i = blockIdx.x*256 + t;
  if (i >= N*80) return;
  int o = i - (i/80)*80;
  float x = xbuf[i];
  out[i] = (o < 32) ? (x*coef[o] + coef[32+o]) : (x*coef[64+(o-32)/3]);
}

extern "C" void kernel_launch(void* const* d_in, const int* in_sizes, int n_in,
                              void* d_out, int out_size, void* d_ws, size_t ws_size,
                              hipStream_t stream) {
  const float* nf     = (const float*)d_in[0];
  const int*   ei     = (const int*)  d_in[1];
  const float* sh     = (const float*)d_in[2];
  const float* radial = (const float*)d_in[3];
  const float* env    = (const float*)d_in[4];
  const float* W1     = (const float*)d_in[5];
  const float* b1     = (const float*)d_in[6];
  const float* W2     = (const float*)d_in[7];
  const float* b2     = (const float*)d_in[8];
  const float* Wq     = (const float*)d_in[9];
  const float* bq     = (const float*)d_in[10];
  const float* Wk     = (const float*)d_in[11];
  const float* bk     = (const float*)d_in[12];
  const float* Wout_s = (const float*)d_in[13];
  const float* Wout_v = (const float*)d_in[14];
  const float* Wg_s   = (const float*)d_in[15];
  const float* Wg_v   = (const float*)d_in[16];
  const float* bn_ws  = (const float*)d_in[17];
  const float* bn_bs  = (const float*)d_in[18];
  const float* bn_wv  = (const float*)d_in[19];

  const int E = in_sizes[4];
  const int N = in_sizes[0] / 80;

  float* ws = (float*)d_ws;
  size_t off = 0;
  __bf16* w2t    = (__bf16*)(ws + off); off += 81920;   // [2][2560][32] bf16
  __bf16* msgs   = (__bf16*)(ws + off); off += (size_t)E*40;  // E*80 bf16
  float* logits_s= ws + off; off += E;
  int* cnt       = (int*)(ws + off); off += N;
  int* cursor    = (int*)(ws + off); off += N;
  float* xbuf    = ws + off; off += (size_t)N*80;
  float* bnacc   = ws + off; off += 80;
  float* kvt     = ws + off; off += (size_t)N*32;
  float* carr    = ws + off; off += N;

  hipMemsetAsync(cnt, 0, (size_t)N*sizeof(int), stream);

  const int nbPrep = 640;                 // 163840/256
  const int nbHist = (E + 255)/256;
  const int nbKv   = (N + 63)/64;
  k_setup<<<nbPrep + nbHist + nbKv, 256, 0, stream>>>(W2, w2t, ei, cnt,
      nf, Wq, bq, Wk, bk, kvt, carr, nbPrep, nbHist, N, E);
  k_scan<<<1, 1024, 0, stream>>>(cnt, cursor, bnacc, N, E);
  k_edge<<<(E + 15)/16, 256, 0, stream>>>(nf, ei, sh, radial, env,
      W1, b1, w2t, b2, kvt, carr, cursor, msgs, logits_s, E);
  k_agg<<<(N + 3)/4, 256, 0, stream>>>(msgs, logits_s, cursor, nf,
      Wout_s, Wout_v, Wg_s, Wg_v, xbuf, bnacc, N);
  k_out<<<(N*80 + 255)/256, 256, 0, stream>>>(xbuf, bnacc, bn_ws, bn_bs, bn_wv,
      (float*)d_out, N);
}